// Round 13
// baseline (314.966 us; speedup 1.0000x reference)
//
#include <hip/hip_runtime.h>
#include <hip/hip_fp16.h>

// TGCN forward, algebraically reduced (H0 = 0 => R/Wr dead, Z*H = 0):
//   deg[d] = #in-edges of d ; dinv = rsqrt(deg+1)
//   xs[s]  = fp16( x[s] * dinv[s] )
//   agg[d] = bf16( dinv[d] * ( sum_{e: dst=d} xs[src] + xs[d]*dinv[d] ) )
//   M = [Wz@Lzw_top | Wh@Lhw_top]  (64x512, bf16, MFMA B-layout), cb = bias fold
//   out = softmax(relu((1-Z)*Ht) @ Wo + bo), Z/Ht from agg@M via MFMA
//
// R1 -> R2: atomic scatter (2700us) -> CSR build + register gather.
// R3 -> R4: scatter 16x write amp -> 2-level bucket sort (793 -> 455us).
// R4 -> R7: register-allocator fights over 64-float M column — dead end.
// R7 -> R8: node GEMM -> mfma_f32_16x16x32_bf16 (412 -> off top-5).
// R8 -> R9: xs = fp16(x*dinv): row 256B -> 128B (gather 124 -> 75).
// R11 -> R12: binning 512thr (occupancy), node_mfma 32-node tiles — both off
// top-5 (320 -> 310). gather back on top at 56us, VALUBusy 61%: inner loop
// spends 16 VALU ops (8 cvt + 8 fma) per 16B payload.
// R12 -> R13: packed fp16 accumulation (v_pk_add_f16): 4 pk_add per uint4,
// unpredicated full batches + zero-selected tail, packed shuffle reduce.
// fp16 accum error ~1.4e-4 into agg — below agg's bf16 quantization (2e-3).

#define SHIFT 8
#define NPB   256          // nodes per bucket (=1<<SHIFT)
#define BMAX  512          // max buckets (n <= 131072 for 17-bit src packing)
#define TILE  8192         // edges per binning block

typedef __attribute__((ext_vector_type(8))) short short8;
typedef __attribute__((ext_vector_type(4))) float floatx4;

__device__ __forceinline__ ushort f2b(float f) {   // fp32 -> bf16 RNE
    union { float f; unsigned u; } v; v.f = f;
    unsigned r = v.u + 0x7FFFu + ((v.u >> 16) & 1u);
    return (ushort)(r >> 16);
}

__global__ __launch_bounds__(256) void bucket_hist_kernel(const int* __restrict__ dsts,
                                                          int* __restrict__ bdeg,
                                                          int E, int B) {
    __shared__ int h[BMAX];
    for (int i = threadIdx.x; i < B; i += 256) h[i] = 0;
    __syncthreads();
    for (int e = blockIdx.x * 256 + threadIdx.x; e < E; e += gridDim.x * 256)
        atomicAdd(&h[((unsigned)dsts[e]) >> SHIFT], 1);
    __syncthreads();
    for (int i = threadIdx.x; i < B; i += 256)
        if (h[i]) atomicAdd(&bdeg[i], h[i]);
}

__global__ __launch_bounds__(512) void bucket_prefix_kernel(const int* __restrict__ bdeg,
                                                            int* __restrict__ bbase,
                                                            int* __restrict__ bcur, int B) {
    __shared__ int sv[BMAX];
    int tid = threadIdx.x;
    int v = (tid < B) ? bdeg[tid] : 0;
    sv[tid] = v;
    __syncthreads();
    for (int off = 1; off < BMAX; off <<= 1) {
        int t = (tid >= off) ? sv[tid - off] : 0;
        __syncthreads();
        sv[tid] += t;
        __syncthreads();
    }
    int excl = sv[tid] - v;
    if (tid < B) { bbase[tid] = excl; bcur[tid] = excl; }
}

// tile of 8192 edges, 512 threads: LDS histogram -> one global cursor atomic
// per (block,bucket) -> packed (dstLocal<<17 | src) written in ~21-entry runs
__global__ __launch_bounds__(512) void binning_kernel(const int* __restrict__ srcs,
                                                      const int* __restrict__ dsts,
                                                      int* __restrict__ bcur,
                                                      int* __restrict__ staging,
                                                      int E, int B) {
    __shared__ int h[BMAX];
    __shared__ int cur[BMAX];
    int tile0 = blockIdx.x * TILE;
    for (int i = threadIdx.x; i < B; i += 512) h[i] = 0;
    __syncthreads();
#pragma unroll 4
    for (int j = 0; j < TILE / 512; ++j) {
        int e = tile0 + j * 512 + threadIdx.x;
        if (e < E) atomicAdd(&h[((unsigned)dsts[e]) >> SHIFT], 1);
    }
    __syncthreads();
    for (int i = threadIdx.x; i < B; i += 512)
        cur[i] = h[i] ? atomicAdd(&bcur[i], h[i]) : 0;
    __syncthreads();
#pragma unroll 4
    for (int j = 0; j < TILE / 512; ++j) {
        int e = tile0 + j * 512 + threadIdx.x;
        if (e < E) {
            int d = dsts[e], s = srcs[e];
            int b = ((unsigned)d) >> SHIFT;
            int pos = atomicAdd(&cur[b], 1);
            staging[pos] = ((d & (NPB - 1)) << 17) | s;
        }
    }
}

// one block (512 thr) per bucket: per-node LDS histogram + scan ->
// start/deg/dinv, then scatter srcs inside the bucket's private csr window
__global__ __launch_bounds__(512) void finalize_kernel(const int* __restrict__ staging,
                                                       const int* __restrict__ bdeg,
                                                       const int* __restrict__ bbase,
                                                       int* __restrict__ csr,
                                                       int* __restrict__ deg,
                                                       int* __restrict__ start,
                                                       float* __restrict__ dinv, int n) {
    int b = blockIdx.x;
    int base = bbase[b], count = bdeg[b];
    __shared__ int nd[NPB];
    __shared__ int sv[NPB];
    __shared__ int ncur[NPB];
    int tid = threadIdx.x;
    if (tid < NPB) nd[tid] = 0;
    __syncthreads();
    for (int i = tid; i < count; i += 512)
        atomicAdd(&nd[staging[base + i] >> 17], 1);
    __syncthreads();
    int d0 = 0;
    if (tid < NPB) { d0 = nd[tid]; sv[tid] = d0; }
    __syncthreads();
    for (int off = 1; off < NPB; off <<= 1) {
        int t = 0;
        if (tid < NPB && tid >= off) t = sv[tid - off];
        __syncthreads();
        if (tid < NPB) sv[tid] += t;
        __syncthreads();
    }
    if (tid < NPB) {
        int excl = sv[tid] - d0;
        ncur[tid] = excl;
        int node = (b << SHIFT) + tid;
        if (node < n) {
            start[node] = base + excl;
            deg[node] = d0;
            dinv[node] = rsqrtf((float)d0 + 1.0f);
        }
    }
    __syncthreads();
    for (int i = tid; i < count; i += 512) {
        int p = staging[base + i];
        int pos = atomicAdd(&ncur[p >> 17], 1);
        csr[base + pos] = p & 0x1FFFF;
    }
}

// xs[s][c] = fp16( x[s][c] * dinv[s] ) — one thread per 4 channels
__global__ __launch_bounds__(256) void xs_kernel(const float* __restrict__ x,
                                                 const float* __restrict__ dinv,
                                                 __half* __restrict__ xs, int total) {
    int i = blockIdx.x * 256 + threadIdx.x;   // over n*16 float4 groups
    if (i >= total) return;
    float dn = dinv[i >> 4];
    float4 v = ((const float4*)x)[i];
    __half2 a = __floats2half2_rn(v.x * dn, v.y * dn);
    __half2 b = __floats2half2_rn(v.z * dn, v.w * dn);
    ((__half2*)xs)[i * 2 + 0] = a;
    ((__half2*)xs)[i * 2 + 1] = b;
}

// one wave per node. Lane = (edge_group 0..7) x (chunk 0..7). Per 64-edge
// chunk: ONE coalesced csr load (indices via shfl). Accumulate in PACKED fp16
// (v_pk_add_f16, 4 ops/uint4 vs 16 cvt+fma): full 16-edge batches
// unpredicated, wave-uniform ragged tail zero-selected. Packed shfl reduce.
__global__ __launch_bounds__(256) void gather_kernel(const int* __restrict__ csr,
                                                     const int* __restrict__ start,
                                                     const int* __restrict__ deg,
                                                     const __half* __restrict__ xs,
                                                     const float* __restrict__ dinv,
                                                     ushort* __restrict__ aggb, int n) {
    int wave = threadIdx.x >> 6;
    int lane = threadIdx.x & 63;
    int node = blockIdx.x * 4 + wave;
    if (node >= n) return;
    int eg = lane >> 3;      // edge group 0..7
    int c  = lane & 7;       // 16B chunk (8 halfs)
    int s0 = start[node];
    int d  = deg[node];
    __half2 hz = __float2half2_rn(0.f);
    __half2 hacc[4] = {hz, hz, hz, hz};
    for (int chunk = 0; chunk < d; chunk += 64) {
        int nrem = d - chunk;
        if (nrem > 64) nrem = 64;
        int ml = lane < nrem ? lane : nrem - 1;
        int idx = csr[s0 + chunk + ml];          // one coalesced load / chunk
        int full = nrem & ~15;
        for (int base = 0; base < full; base += 16) {   // unpredicated batches
            int i0 = __shfl(idx, base + eg);
            int i1 = __shfl(idx, base + 8 + eg);
            union { uint4 u; __half2 h[4]; } p0, p1;
            p0.u = *(const uint4*)(xs + (size_t)i0 * 64 + c * 8);
            p1.u = *(const uint4*)(xs + (size_t)i1 * 64 + c * 8);
#pragma unroll
            for (int t = 0; t < 4; ++t) hacc[t] = __hadd2(hacc[t], p0.h[t]);
#pragma unroll
            for (int t = 0; t < 4; ++t) hacc[t] = __hadd2(hacc[t], p1.h[t]);
        }
        if (full < nrem) {   // wave-uniform ragged tail (< 16 edges)
            int e0 = full + eg;
            int e1 = full + 8 + eg;
            int i0 = __shfl(idx, e0 < nrem ? e0 : nrem - 1);
            int i1 = __shfl(idx, e1 < nrem ? e1 : nrem - 1);
            union { uint4 u; __half2 h[4]; } p0, p1;
            p0.u = *(const uint4*)(xs + (size_t)i0 * 64 + c * 8);
            p1.u = *(const uint4*)(xs + (size_t)i1 * 64 + c * 8);
            if (e0 >= nrem) p0.u = make_uint4(0u, 0u, 0u, 0u);
            if (e1 >= nrem) p1.u = make_uint4(0u, 0u, 0u, 0u);
#pragma unroll
            for (int t = 0; t < 4; ++t) hacc[t] = __hadd2(hacc[t], p0.h[t]);
#pragma unroll
            for (int t = 0; t < 4; ++t) hacc[t] = __hadd2(hacc[t], p1.h[t]);
        }
    }
    // packed cross-lane reduce of the 8 edge groups down to eg==0
#pragma unroll
    for (int off = 32; off >= 8; off >>= 1) {
#pragma unroll
        for (int t = 0; t < 4; ++t) {
            union { __half2 h; int i; } u;
            u.h = hacc[t];
            u.i = __shfl_down(u.i, off);
            hacc[t] = __hadd2(hacc[t], u.h);
        }
    }
    if (eg == 0) {
        float dn = dinv[node];
        union { uint4 u; __half2 h[4]; } p;
        p.u = *(const uint4*)(xs + (size_t)node * 64 + c * 8);
        uint4 o;
        unsigned* ow = (unsigned*)&o;
#pragma unroll
        for (int t = 0; t < 4; ++t) {
            float2 a = __half22float2(hacc[t]);
            float2 f = __half22float2(p.h[t]);
            float v0 = dn * fmaf(f.x, dn, a.x);
            float v1 = dn * fmaf(f.y, dn, a.y);
            ow[t] = (unsigned)f2b(v0) | ((unsigned)f2b(v1) << 16);
        }
        ((uint4*)(aggb + (size_t)node * 64))[c] = o;
    }
}

// Mb[j][k] = bf16( sum_t W[k][t] * L[t][j] ), j in [0,512): j<256 z, else h.
// Row-major [512][64] bf16 == MFMA B-operand order. cb[j] = bias fold.
__global__ __launch_bounds__(64) void build_m_kernel(
    const float* __restrict__ Wz, const float* __restrict__ bz,
    const float* __restrict__ Wh, const float* __restrict__ bh,
    const float* __restrict__ Lzw, const float* __restrict__ Lzb,
    const float* __restrict__ Lhw, const float* __restrict__ Lhb,
    ushort* __restrict__ Mb, float* __restrict__ cb) {
    int j = blockIdx.x;          // 0..511
    int k = threadIdx.x;         // 0..63
    int which = j >> 8;
    int jj = j & 255;
    const float* W  = which ? Wh  : Wz;
    const float* bv = which ? bh  : bz;
    const float* L  = which ? Lhw : Lzw;   // [512,256]; rows 0..255 only (H0=0)
    const float* Lb = which ? Lhb : Lzb;
    float acc = 0.f;
    for (int t = 0; t < 256; ++t) acc = fmaf(W[k * 256 + t], L[t * 256 + jj], acc);
    Mb[j * 64 + k] = f2b(acc);
    if (k == 0) {
        float a = 0.f;
        for (int t = 0; t < 256; ++t) a = fmaf(bv[t], L[t * 256 + jj], a);
        cb[j] = a + Lb[jj];
    }
}

// 512 threads = 8 waves. Wave w owns cols w*32..w*32+31 for BOTH gates
// (z and ht meet in-register, h=relu((1-z)*ht) -> one h-plane in LDS).
// 32-node tiles: 16 MFMA between barriers, head 16 thr/node, grid 1024
// co-resident so b-frag entry loads are paid once per block.
__global__ __launch_bounds__(512) void node_mfma_kernel(
    const ushort* __restrict__ aggb,   // [n][64] bf16
    const ushort* __restrict__ Mb,     // [512][64] bf16 (B layout)
    const float* __restrict__ cb,      // [512]
    const float* __restrict__ Wo, const float* __restrict__ bo,
    float* __restrict__ out, int n) {
    int tid  = threadIdx.x;
    int w    = tid >> 6;
    int lane = tid & 63;
    int nidx = lane & 15;
    int quad = lane >> 4;
    short8 bfz[2][2], bfh[2][2];
    float cbz[2], cbh[2];
#pragma unroll
    for (int cg = 0; cg < 2; ++cg) {
        int colZ = (w << 5) + (cg << 4) + nidx;
        int colH = 256 + colZ;
#pragma unroll
        for (int s = 0; s < 2; ++s) {
            bfz[cg][s] = *(const short8*)(Mb + colZ * 64 + s * 32 + quad * 8);
            bfh[cg][s] = *(const short8*)(Mb + colH * 64 + s * 32 + quad * 8);
        }
        cbz[cg] = cb[colZ];
        cbh[cg] = cb[colH];
    }
    __shared__ float sH[32][260];    // 33 KB h-plane (260 pad: 2-way on stores)
    __shared__ float sWo[4][256];
    if (tid < 256) {
#pragma unroll
        for (int o = 0; o < 4; ++o) sWo[o][tid] = Wo[tid * 4 + o];
    }
    float bo0 = bo[0], bo1 = bo[1], bo2 = bo[2], bo3 = bo[3];
    int ntiles = (n + 31) >> 5;
    for (int tile = blockIdx.x; tile < ntiles; tile += gridDim.x) {
        int node0 = tile << 5;
        int nA0 = node0 + nidx;
        int nA1 = node0 + 16 + nidx;
        if (nA0 >= n) nA0 = n - 1;   // clamp; stores are guarded
        if (nA1 >= n) nA1 = n - 1;
        const ushort* ar0 = aggb + (size_t)nA0 * 64;
        const ushort* ar1 = aggb + (size_t)nA1 * 64;
        short8 a00 = *(const short8*)(ar0 + quad * 8);
        short8 a01 = *(const short8*)(ar0 + 32 + quad * 8);
        short8 a10 = *(const short8*)(ar1 + quad * 8);
        short8 a11 = *(const short8*)(ar1 + 32 + quad * 8);
#pragma unroll
        for (int cg = 0; cg < 2; ++cg) {
            int col = (w << 5) + (cg << 4) + nidx;
#pragma unroll
            for (int grp = 0; grp < 2; ++grp) {
                short8 a0 = grp ? a10 : a00;
                short8 a1 = grp ? a11 : a01;
                floatx4 cz = {cbz[cg], cbz[cg], cbz[cg], cbz[cg]};
                cz = __builtin_amdgcn_mfma_f32_16x16x32_bf16(a0, bfz[cg][0], cz, 0, 0, 0);
                cz = __builtin_amdgcn_mfma_f32_16x16x32_bf16(a1, bfz[cg][1], cz, 0, 0, 0);
                floatx4 chh = {cbh[cg], cbh[cg], cbh[cg], cbh[cg]};
                chh = __builtin_amdgcn_mfma_f32_16x16x32_bf16(a0, bfh[cg][0], chh, 0, 0, 0);
                chh = __builtin_amdgcn_mfma_f32_16x16x32_bf16(a1, bfh[cg][1], chh, 0, 0, 0);
#pragma unroll
                for (int r = 0; r < 4; ++r) {
                    int row = (grp << 4) + (quad << 2) + r;   // node within tile
                    float zc = 1.0f / (1.0f + __expf(cz[r]));    // 1 - sigmoid
                    float th = 1.0f - 2.0f / (1.0f + __expf(2.0f * chh[r]));
                    sH[row][col] = fmaxf(zc * th, 0.0f);
                }
            }
        }
        __syncthreads();
        {   // head: 16 threads per node, 16 channels each
            int nb = tid >> 4, g = tid & 15;
            float l0 = 0.f, l1 = 0.f, l2 = 0.f, l3 = 0.f;
#pragma unroll
            for (int ii = 0; ii < 16; ++ii) {
                int ch = g + 16 * ii;
                float hv = sH[nb][ch];
                l0 = fmaf(hv, sWo[0][ch], l0);
                l1 = fmaf(hv, sWo[1][ch], l1);
                l2 = fmaf(hv, sWo[2][ch], l2);
                l3 = fmaf(hv, sWo[3][ch], l3);
            }
#pragma unroll
            for (int off = 8; off > 0; off >>= 1) {
                l0 += __shfl_down(l0, off, 16);
                l1 += __shfl_down(l1, off, 16);
                l2 += __shfl_down(l2, off, 16);
                l3 += __shfl_down(l3, off, 16);
            }
            int node = node0 + nb;
            if (g == 0 && node < n) {
                float v0 = l0 + bo0, v1 = l1 + bo1, v2 = l2 + bo2, v3 = l3 + bo3;
                float mx = fmaxf(fmaxf(v0, v1), fmaxf(v2, v3));
                float e0 = __expf(v0 - mx), e1 = __expf(v1 - mx);
                float e2 = __expf(v2 - mx), e3 = __expf(v3 - mx);
                float inv = 1.0f / (e0 + e1 + e2 + e3);
                float4 o;
                o.x = e0 * inv; o.y = e1 * inv; o.z = e2 * inv; o.w = e3 * inv;
                ((float4*)out)[node] = o;
            }
        }
        __syncthreads();
    }
}

extern "C" void kernel_launch(void* const* d_in, const int* in_sizes, int n_in,
                              void* d_out, int out_size, void* d_ws, size_t ws_size,
                              hipStream_t stream) {
    const float* x   = (const float*)d_in[0];
    const int*  eidx = (const int*)d_in[1];
    const float* Wz  = (const float*)d_in[2];
    const float* bz  = (const float*)d_in[3];
    // d_in[4]=Wr, d_in[5]=br : dead (H0 = 0)
    const float* Wh  = (const float*)d_in[6];
    const float* bh  = (const float*)d_in[7];
    const float* Lzw = (const float*)d_in[8];
    const float* Lzb = (const float*)d_in[9];
    // d_in[10]=Lrw, d_in[11]=Lrb : dead
    const float* Lhw = (const float*)d_in[12];
    const float* Lhb = (const float*)d_in[13];
    const float* Wo  = (const float*)d_in[14];
    const float* bo  = (const float*)d_in[15];
    float* out = (float*)d_out;

    int n = in_sizes[0] / 64;
    int E = in_sizes[1] / 2;
    const int* srcs = eidx;
    const int* dsts = eidx + E;
    int B = (n + NPB - 1) >> SHIFT;

    size_t na = ((size_t)n + 3) & ~(size_t)3;
    size_t aggBytes = (size_t)n * 64 * 2;                 // bf16 agg
    size_t stageBytes = (size_t)E * 4 + 16;               // staging (aliases agg)
    size_t bigBytes = (aggBytes > stageBytes ? aggBytes : stageBytes);
    bigBytes = (bigBytes + 255) & ~(size_t)255;

    char* ws = (char*)d_ws;
    int*   deg   = (int*)ws;    ws += na * 4;
    int*   start = (int*)ws;    ws += na * 4;
    float* dinv  = (float*)ws;  ws += na * 4;
    int*   bdeg  = (int*)ws;    ws += BMAX * 4;
    int*   bbase = (int*)ws;    ws += BMAX * 4;
    int*   bcur  = (int*)ws;    ws += BMAX * 4;
    int*   csr   = (int*)ws;    ws += (size_t)E * 4;
    __half* xs   = (__half*)ws; ws += (size_t)n * 64 * 2;
    ushort* aggb = (ushort*)ws;
    int*   staging = (int*)aggb;   // aliases aggb: staging dead before gather
    ws += bigBytes;
    ushort* Mb   = (ushort*)ws; ws += 512 * 64 * 2;
    float* cb    = (float*)ws;  ws += 512 * 4;

    hipMemsetAsync(bdeg, 0, BMAX * sizeof(int), stream);

    bucket_hist_kernel<<<1024, 256, 0, stream>>>(dsts, bdeg, E, B);
    bucket_prefix_kernel<<<1, BMAX, 0, stream>>>(bdeg, bbase, bcur, B);
    binning_kernel<<<(E + TILE - 1) / TILE, 512, 0, stream>>>(srcs, dsts, bcur,
                                                              staging, E, B);
    finalize_kernel<<<B, 512, 0, stream>>>(staging, bdeg, bbase, csr, deg, start,
                                           dinv, n);
    build_m_kernel<<<512, 64, 0, stream>>>(Wz, bz, Wh, bh, Lzw, Lzb, Lhw, Lhb,
                                           Mb, cb);
    xs_kernel<<<(n * 16 + 255) / 256, 256, 0, stream>>>(x, dinv, xs, n * 16);
    gather_kernel<<<(n + 3) / 4, 256, 0, stream>>>(csr, start, deg, xs, dinv,
                                                   aggb, n);
    node_mfma_kernel<<<1024, 512, 0, stream>>>(aggb, Mb, cb, Wo, bo, out, n);
}

// Round 14
// 303.662 us; speedup vs baseline: 1.0372x; 1.0372x over previous
//
#include <hip/hip_runtime.h>
#include <hip/hip_fp16.h>

// TGCN forward, algebraically reduced (H0 = 0 => R/Wr dead, Z*H = 0):
//   deg[d] = #in-edges of d ; dinv = rsqrt(deg+1)
//   xs[s]  = fp16( x[s] * dinv[s] )
//   agg[d] = bf16( dinv[d] * ( sum_{e: dst=d} xs[src] + xs[d]*dinv[d] ) )
//   M = [Wz@Lzw_top | Wh@Lhw_top]  (64x512, bf16, MFMA B-layout), cb = bias fold
//   out = softmax(relu((1-Z)*Ht) @ Wo + bo), Z/Ht from agg@M via MFMA
//
// R1 -> R2: atomic scatter (2700us) -> CSR build + register gather.
// R3 -> R4: scatter 16x write amp -> 2-level bucket sort (793 -> 455us).
// R7 -> R8: node GEMM -> mfma_f32_16x16x32_bf16 (412 -> off top-5).
// R8 -> R9: xs = fp16(x*dinv): row 256B -> 128B (gather 124 -> 75).
// R12 -> R13: gather packed-fp16 accum: VALUBusy 61 -> 47% but dur flat —
// gather is L2-miss-footprint bound (160MB @ 3.3TB/s), not VALU bound.
// R13 -> R14: binning's 55.7us = 153K atomicAdd-with-return on 391 cursor
// addresses (391-deep serialization x ~300cyc ~= 49us, VALUBusy 2.4%).
// Replaced by deterministic offsets: per-tile hist -> per-bucket block scan
// -> scatter with LDS-only cursors. Zero global atomics in the hot path.

#define SHIFT 8
#define NPB   256          // nodes per bucket (=1<<SHIFT)
#define BMAX  512          // max buckets (n <= 131072 for 17-bit src packing)
#define TILE  8192         // edges per tile (hist/scatter blocks)

typedef __attribute__((ext_vector_type(8))) short short8;
typedef __attribute__((ext_vector_type(4))) float floatx4;

__device__ __forceinline__ ushort f2b(float f) {   // fp32 -> bf16 RNE
    union { float f; unsigned u; } v; v.f = f;
    unsigned r = v.u + 0x7FFFu + ((v.u >> 16) & 1u);
    return (ushort)(r >> 16);
}

// per-tile bucket histogram -> histg[block][bucket]
__global__ __launch_bounds__(512) void hist_kernel(const int* __restrict__ dsts,
                                                   int* __restrict__ histg,
                                                   int E, int B) {
    __shared__ int h[BMAX];
    for (int i = threadIdx.x; i < B; i += 512) h[i] = 0;
    __syncthreads();
    int tile0 = blockIdx.x * TILE;
#pragma unroll 4
    for (int j = 0; j < TILE / 512; ++j) {
        int e = tile0 + j * 512 + threadIdx.x;
        if (e < E) atomicAdd(&h[((unsigned)dsts[e]) >> SHIFT], 1);
    }
    __syncthreads();
    for (int i = threadIdx.x; i < B; i += 512)
        histg[blockIdx.x * BMAX + i] = h[i];
}

// one block per bucket: exclusive scan of histg[.][b] over blocks (in place),
// column total -> bdeg[b]
__global__ __launch_bounds__(512) void colscan_kernel(int* __restrict__ histg,
                                                      int* __restrict__ bdeg,
                                                      int nT) {
    int b = blockIdx.x;
    int tid = threadIdx.x;
    __shared__ int sv[512];
    int v = (tid < nT) ? histg[tid * BMAX + b] : 0;
    sv[tid] = v;
    __syncthreads();
    for (int off = 1; off < 512; off <<= 1) {
        int t = (tid >= off) ? sv[tid - off] : 0;
        __syncthreads();
        sv[tid] += t;
        __syncthreads();
    }
    if (tid < nT) histg[tid * BMAX + b] = sv[tid] - v;   // exclusive
    if (tid == 0) bdeg[b] = sv[511];                      // column total
}

__global__ __launch_bounds__(512) void bucket_prefix_kernel(const int* __restrict__ bdeg,
                                                            int* __restrict__ bbase, int B) {
    __shared__ int sv[BMAX];
    int tid = threadIdx.x;
    int v = (tid < B) ? bdeg[tid] : 0;
    sv[tid] = v;
    __syncthreads();
    for (int off = 1; off < BMAX; off <<= 1) {
        int t = (tid >= off) ? sv[tid - off] : 0;
        __syncthreads();
        sv[tid] += t;
        __syncthreads();
    }
    if (tid < B) bbase[tid] = sv[tid] - v;
}

// tile scatter with deterministic run bases (bbase[b] + histg[blk][b]) and
// LDS-only cursors — no global atomics. Packed (dstLocal<<17 | src).
__global__ __launch_bounds__(512) void scatter2_kernel(const int* __restrict__ srcs,
                                                       const int* __restrict__ dsts,
                                                       const int* __restrict__ histg,
                                                       const int* __restrict__ bbase,
                                                       int* __restrict__ staging,
                                                       int E, int B) {
    __shared__ int cur[BMAX];
    int tile0 = blockIdx.x * TILE;
    for (int i = threadIdx.x; i < B; i += 512)
        cur[i] = bbase[i] + histg[blockIdx.x * BMAX + i];
    __syncthreads();
#pragma unroll 4
    for (int j = 0; j < TILE / 512; ++j) {
        int e = tile0 + j * 512 + threadIdx.x;
        if (e < E) {
            int d = dsts[e], s = srcs[e];
            int b = ((unsigned)d) >> SHIFT;
            int pos = atomicAdd(&cur[b], 1);   // LDS atomic only
            staging[pos] = ((d & (NPB - 1)) << 17) | s;
        }
    }
}

// one block (512 thr) per bucket: per-node LDS histogram + scan ->
// start/deg/dinv, then scatter srcs inside the bucket's private csr window
__global__ __launch_bounds__(512) void finalize_kernel(const int* __restrict__ staging,
                                                       const int* __restrict__ bdeg,
                                                       const int* __restrict__ bbase,
                                                       int* __restrict__ csr,
                                                       int* __restrict__ deg,
                                                       int* __restrict__ start,
                                                       float* __restrict__ dinv, int n) {
    int b = blockIdx.x;
    int base = bbase[b], count = bdeg[b];
    __shared__ int nd[NPB];
    __shared__ int sv[NPB];
    __shared__ int ncur[NPB];
    int tid = threadIdx.x;
    if (tid < NPB) nd[tid] = 0;
    __syncthreads();
    for (int i = tid; i < count; i += 512)
        atomicAdd(&nd[staging[base + i] >> 17], 1);
    __syncthreads();
    int d0 = 0;
    if (tid < NPB) { d0 = nd[tid]; sv[tid] = d0; }
    __syncthreads();
    for (int off = 1; off < NPB; off <<= 1) {
        int t = 0;
        if (tid < NPB && tid >= off) t = sv[tid - off];
        __syncthreads();
        if (tid < NPB) sv[tid] += t;
        __syncthreads();
    }
    if (tid < NPB) {
        int excl = sv[tid] - d0;
        ncur[tid] = excl;
        int node = (b << SHIFT) + tid;
        if (node < n) {
            start[node] = base + excl;
            deg[node] = d0;
            dinv[node] = rsqrtf((float)d0 + 1.0f);
        }
    }
    __syncthreads();
    for (int i = tid; i < count; i += 512) {
        int p = staging[base + i];
        int pos = atomicAdd(&ncur[p >> 17], 1);
        csr[base + pos] = p & 0x1FFFF;
    }
}

// xs[s][c] = fp16( x[s][c] * dinv[s] ) — one thread per 4 channels
__global__ __launch_bounds__(256) void xs_kernel(const float* __restrict__ x,
                                                 const float* __restrict__ dinv,
                                                 __half* __restrict__ xs, int total) {
    int i = blockIdx.x * 256 + threadIdx.x;   // over n*16 float4 groups
    if (i >= total) return;
    float dn = dinv[i >> 4];
    float4 v = ((const float4*)x)[i];
    __half2 a = __floats2half2_rn(v.x * dn, v.y * dn);
    __half2 b = __floats2half2_rn(v.z * dn, v.w * dn);
    ((__half2*)xs)[i * 2 + 0] = a;
    ((__half2*)xs)[i * 2 + 1] = b;
}

// one wave per node. Lane = (edge_group 0..7) x (chunk 0..7). Per 64-edge
// chunk: ONE coalesced csr load (indices via shfl). Packed fp16 accumulation.
__global__ __launch_bounds__(256) void gather_kernel(const int* __restrict__ csr,
                                                     const int* __restrict__ start,
                                                     const int* __restrict__ deg,
                                                     const __half* __restrict__ xs,
                                                     const float* __restrict__ dinv,
                                                     ushort* __restrict__ aggb, int n) {
    int wave = threadIdx.x >> 6;
    int lane = threadIdx.x & 63;
    int node = blockIdx.x * 4 + wave;
    if (node >= n) return;
    int eg = lane >> 3;      // edge group 0..7
    int c  = lane & 7;       // 16B chunk (8 halfs)
    int s0 = start[node];
    int d  = deg[node];
    __half2 hz = __float2half2_rn(0.f);
    __half2 hacc[4] = {hz, hz, hz, hz};
    for (int chunk = 0; chunk < d; chunk += 64) {
        int nrem = d - chunk;
        if (nrem > 64) nrem = 64;
        int ml = lane < nrem ? lane : nrem - 1;
        int idx = csr[s0 + chunk + ml];          // one coalesced load / chunk
        int full = nrem & ~15;
        for (int base = 0; base < full; base += 16) {   // unpredicated batches
            int i0 = __shfl(idx, base + eg);
            int i1 = __shfl(idx, base + 8 + eg);
            union { uint4 u; __half2 h[4]; } p0, p1;
            p0.u = *(const uint4*)(xs + (size_t)i0 * 64 + c * 8);
            p1.u = *(const uint4*)(xs + (size_t)i1 * 64 + c * 8);
#pragma unroll
            for (int t = 0; t < 4; ++t) hacc[t] = __hadd2(hacc[t], p0.h[t]);
#pragma unroll
            for (int t = 0; t < 4; ++t) hacc[t] = __hadd2(hacc[t], p1.h[t]);
        }
        if (full < nrem) {   // wave-uniform ragged tail (< 16 edges)
            int e0 = full + eg;
            int e1 = full + 8 + eg;
            int i0 = __shfl(idx, e0 < nrem ? e0 : nrem - 1);
            int i1 = __shfl(idx, e1 < nrem ? e1 : nrem - 1);
            union { uint4 u; __half2 h[4]; } p0, p1;
            p0.u = *(const uint4*)(xs + (size_t)i0 * 64 + c * 8);
            p1.u = *(const uint4*)(xs + (size_t)i1 * 64 + c * 8);
            if (e0 >= nrem) p0.u = make_uint4(0u, 0u, 0u, 0u);
            if (e1 >= nrem) p1.u = make_uint4(0u, 0u, 0u, 0u);
#pragma unroll
            for (int t = 0; t < 4; ++t) hacc[t] = __hadd2(hacc[t], p0.h[t]);
#pragma unroll
            for (int t = 0; t < 4; ++t) hacc[t] = __hadd2(hacc[t], p1.h[t]);
        }
    }
    // packed cross-lane reduce of the 8 edge groups down to eg==0
#pragma unroll
    for (int off = 32; off >= 8; off >>= 1) {
#pragma unroll
        for (int t = 0; t < 4; ++t) {
            union { __half2 h; int i; } u;
            u.h = hacc[t];
            u.i = __shfl_down(u.i, off);
            hacc[t] = __hadd2(hacc[t], u.h);
        }
    }
    if (eg == 0) {
        float dn = dinv[node];
        union { uint4 u; __half2 h[4]; } p;
        p.u = *(const uint4*)(xs + (size_t)node * 64 + c * 8);
        uint4 o;
        unsigned* ow = (unsigned*)&o;
#pragma unroll
        for (int t = 0; t < 4; ++t) {
            float2 a = __half22float2(hacc[t]);
            float2 f = __half22float2(p.h[t]);
            float v0 = dn * fmaf(f.x, dn, a.x);
            float v1 = dn * fmaf(f.y, dn, a.y);
            ow[t] = (unsigned)f2b(v0) | ((unsigned)f2b(v1) << 16);
        }
        ((uint4*)(aggb + (size_t)node * 64))[c] = o;
    }
}

// Mb[j][k] = bf16( sum_t W[k][t] * L[t][j] ), j in [0,512): j<256 z, else h.
// Row-major [512][64] bf16 == MFMA B-operand order. cb[j] = bias fold.
__global__ __launch_bounds__(64) void build_m_kernel(
    const float* __restrict__ Wz, const float* __restrict__ bz,
    const float* __restrict__ Wh, const float* __restrict__ bh,
    const float* __restrict__ Lzw, const float* __restrict__ Lzb,
    const float* __restrict__ Lhw, const float* __restrict__ Lhb,
    ushort* __restrict__ Mb, float* __restrict__ cb) {
    int j = blockIdx.x;          // 0..511
    int k = threadIdx.x;         // 0..63
    int which = j >> 8;
    int jj = j & 255;
    const float* W  = which ? Wh  : Wz;
    const float* bv = which ? bh  : bz;
    const float* L  = which ? Lhw : Lzw;   // [512,256]; rows 0..255 only (H0=0)
    const float* Lb = which ? Lhb : Lzb;
    float acc = 0.f;
    for (int t = 0; t < 256; ++t) acc = fmaf(W[k * 256 + t], L[t * 256 + jj], acc);
    Mb[j * 64 + k] = f2b(acc);
    if (k == 0) {
        float a = 0.f;
        for (int t = 0; t < 256; ++t) a = fmaf(bv[t], L[t * 256 + jj], a);
        cb[j] = a + Lb[jj];
    }
}

// 512 threads = 8 waves. Wave w owns cols w*32..w*32+31 for BOTH gates
// (z and ht meet in-register, h=relu((1-z)*ht) -> one h-plane in LDS).
// 32-node tiles: 16 MFMA between barriers, head 16 thr/node, grid 1024
// co-resident so b-frag entry loads are paid once per block.
__global__ __launch_bounds__(512) void node_mfma_kernel(
    const ushort* __restrict__ aggb,   // [n][64] bf16
    const ushort* __restrict__ Mb,     // [512][64] bf16 (B layout)
    const float* __restrict__ cb,      // [512]
    const float* __restrict__ Wo, const float* __restrict__ bo,
    float* __restrict__ out, int n) {
    int tid  = threadIdx.x;
    int w    = tid >> 6;
    int lane = tid & 63;
    int nidx = lane & 15;
    int quad = lane >> 4;
    short8 bfz[2][2], bfh[2][2];
    float cbz[2], cbh[2];
#pragma unroll
    for (int cg = 0; cg < 2; ++cg) {
        int colZ = (w << 5) + (cg << 4) + nidx;
        int colH = 256 + colZ;
#pragma unroll
        for (int s = 0; s < 2; ++s) {
            bfz[cg][s] = *(const short8*)(Mb + colZ * 64 + s * 32 + quad * 8);
            bfh[cg][s] = *(const short8*)(Mb + colH * 64 + s * 32 + quad * 8);
        }
        cbz[cg] = cb[colZ];
        cbh[cg] = cb[colH];
    }
    __shared__ float sH[32][260];    // 33 KB h-plane (260 pad: 2-way on stores)
    __shared__ float sWo[4][256];
    if (tid < 256) {
#pragma unroll
        for (int o = 0; o < 4; ++o) sWo[o][tid] = Wo[tid * 4 + o];
    }
    float bo0 = bo[0], bo1 = bo[1], bo2 = bo[2], bo3 = bo[3];
    int ntiles = (n + 31) >> 5;
    for (int tile = blockIdx.x; tile < ntiles; tile += gridDim.x) {
        int node0 = tile << 5;
        int nA0 = node0 + nidx;
        int nA1 = node0 + 16 + nidx;
        if (nA0 >= n) nA0 = n - 1;   // clamp; stores are guarded
        if (nA1 >= n) nA1 = n - 1;
        const ushort* ar0 = aggb + (size_t)nA0 * 64;
        const ushort* ar1 = aggb + (size_t)nA1 * 64;
        short8 a00 = *(const short8*)(ar0 + quad * 8);
        short8 a01 = *(const short8*)(ar0 + 32 + quad * 8);
        short8 a10 = *(const short8*)(ar1 + quad * 8);
        short8 a11 = *(const short8*)(ar1 + 32 + quad * 8);
#pragma unroll
        for (int cg = 0; cg < 2; ++cg) {
            int col = (w << 5) + (cg << 4) + nidx;
#pragma unroll
            for (int grp = 0; grp < 2; ++grp) {
                short8 a0 = grp ? a10 : a00;
                short8 a1 = grp ? a11 : a01;
                floatx4 cz = {cbz[cg], cbz[cg], cbz[cg], cbz[cg]};
                cz = __builtin_amdgcn_mfma_f32_16x16x32_bf16(a0, bfz[cg][0], cz, 0, 0, 0);
                cz = __builtin_amdgcn_mfma_f32_16x16x32_bf16(a1, bfz[cg][1], cz, 0, 0, 0);
                floatx4 chh = {cbh[cg], cbh[cg], cbh[cg], cbh[cg]};
                chh = __builtin_amdgcn_mfma_f32_16x16x32_bf16(a0, bfh[cg][0], chh, 0, 0, 0);
                chh = __builtin_amdgcn_mfma_f32_16x16x32_bf16(a1, bfh[cg][1], chh, 0, 0, 0);
#pragma unroll
                for (int r = 0; r < 4; ++r) {
                    int row = (grp << 4) + (quad << 2) + r;   // node within tile
                    float zc = 1.0f / (1.0f + __expf(cz[r]));    // 1 - sigmoid
                    float th = 1.0f - 2.0f / (1.0f + __expf(2.0f * chh[r]));
                    sH[row][col] = fmaxf(zc * th, 0.0f);
                }
            }
        }
        __syncthreads();
        {   // head: 16 threads per node, 16 channels each
            int nb = tid >> 4, g = tid & 15;
            float l0 = 0.f, l1 = 0.f, l2 = 0.f, l3 = 0.f;
#pragma unroll
            for (int ii = 0; ii < 16; ++ii) {
                int ch = g + 16 * ii;
                float hv = sH[nb][ch];
                l0 = fmaf(hv, sWo[0][ch], l0);
                l1 = fmaf(hv, sWo[1][ch], l1);
                l2 = fmaf(hv, sWo[2][ch], l2);
                l3 = fmaf(hv, sWo[3][ch], l3);
            }
#pragma unroll
            for (int off = 8; off > 0; off >>= 1) {
                l0 += __shfl_down(l0, off, 16);
                l1 += __shfl_down(l1, off, 16);
                l2 += __shfl_down(l2, off, 16);
                l3 += __shfl_down(l3, off, 16);
            }
            int node = node0 + nb;
            if (g == 0 && node < n) {
                float v0 = l0 + bo0, v1 = l1 + bo1, v2 = l2 + bo2, v3 = l3 + bo3;
                float mx = fmaxf(fmaxf(v0, v1), fmaxf(v2, v3));
                float e0 = __expf(v0 - mx), e1 = __expf(v1 - mx);
                float e2 = __expf(v2 - mx), e3 = __expf(v3 - mx);
                float inv = 1.0f / (e0 + e1 + e2 + e3);
                float4 o;
                o.x = e0 * inv; o.y = e1 * inv; o.z = e2 * inv; o.w = e3 * inv;
                ((float4*)out)[node] = o;
            }
        }
        __syncthreads();
    }
}

extern "C" void kernel_launch(void* const* d_in, const int* in_sizes, int n_in,
                              void* d_out, int out_size, void* d_ws, size_t ws_size,
                              hipStream_t stream) {
    const float* x   = (const float*)d_in[0];
    const int*  eidx = (const int*)d_in[1];
    const float* Wz  = (const float*)d_in[2];
    const float* bz  = (const float*)d_in[3];
    // d_in[4]=Wr, d_in[5]=br : dead (H0 = 0)
    const float* Wh  = (const float*)d_in[6];
    const float* bh  = (const float*)d_in[7];
    const float* Lzw = (const float*)d_in[8];
    const float* Lzb = (const float*)d_in[9];
    // d_in[10]=Lrw, d_in[11]=Lrb : dead
    const float* Lhw = (const float*)d_in[12];
    const float* Lhb = (const float*)d_in[13];
    const float* Wo  = (const float*)d_in[14];
    const float* bo  = (const float*)d_in[15];
    float* out = (float*)d_out;

    int n = in_sizes[0] / 64;
    int E = in_sizes[1] / 2;
    const int* srcs = eidx;
    const int* dsts = eidx + E;
    int B = (n + NPB - 1) >> SHIFT;
    int nT = (E + TILE - 1) / TILE;          // tiles (<= 512 for E <= 4.2M)

    size_t na = ((size_t)n + 3) & ~(size_t)3;
    size_t aggBytes = (size_t)n * 64 * 2;                 // bf16 agg
    size_t stageBytes = (size_t)E * 4 + 16;               // staging (aliases agg)
    size_t bigBytes = (aggBytes > stageBytes ? aggBytes : stageBytes);
    bigBytes = (bigBytes + 255) & ~(size_t)255;

    char* ws = (char*)d_ws;
    int*   deg   = (int*)ws;    ws += na * 4;
    int*   start = (int*)ws;    ws += na * 4;
    float* dinv  = (float*)ws;  ws += na * 4;
    int*   bdeg  = (int*)ws;    ws += BMAX * 4;
    int*   bbase = (int*)ws;    ws += BMAX * 4;
    int*   histg = (int*)ws;    ws += (size_t)nT * BMAX * 4;
    int*   csr   = (int*)ws;    ws += (size_t)E * 4;
    __half* xs   = (__half*)ws; ws += (size_t)n * 64 * 2;
    ushort* aggb = (ushort*)ws;
    int*   staging = (int*)aggb;   // aliases aggb: staging dead before gather
    ws += bigBytes;
    ushort* Mb   = (ushort*)ws; ws += 512 * 64 * 2;
    float* cb    = (float*)ws;  ws += 512 * 4;

    hist_kernel<<<nT, 512, 0, stream>>>(dsts, histg, E, B);
    colscan_kernel<<<B, 512, 0, stream>>>(histg, bdeg, nT);
    bucket_prefix_kernel<<<1, BMAX, 0, stream>>>(bdeg, bbase, B);
    scatter2_kernel<<<nT, 512, 0, stream>>>(srcs, dsts, histg, bbase, staging,
                                            E, B);
    finalize_kernel<<<B, 512, 0, stream>>>(staging, bdeg, bbase, csr, deg, start,
                                           dinv, n);
    build_m_kernel<<<512, 64, 0, stream>>>(Wz, bz, Wh, bh, Lzw, Lzb, Lhw, Lhb,
                                           Mb, cb);
    xs_kernel<<<(n * 16 + 255) / 256, 256, 0, stream>>>(x, dinv, xs, n * 16);
    gather_kernel<<<(n + 3) / 4, 256, 0, stream>>>(csr, start, deg, xs, dinv,
                                                   aggb, n);
    node_mfma_kernel<<<1024, 512, 0, stream>>>(aggb, Mb, cb, Wo, bo, out, n);
}

// Round 15
// 275.383 us; speedup vs baseline: 1.1437x; 1.1027x over previous
//
#include <hip/hip_runtime.h>
#include <hip/hip_fp16.h>

// TGCN forward, algebraically reduced (H0 = 0 => R/Wr dead, Z*H = 0):
//   deg[d] = #in-edges of d ; dinv = rsqrt(deg+1)
//   xs[s]  = fp16( x[s] * dinv[s] )
//   agg[d] = bf16( dinv[d] * ( sum_{e: dst=d} xs[src] + xs[d]*dinv[d] ) )
//   M = [Wz@Lzw_top | Wh@Lhw_top]  (64x512, bf16, MFMA B-layout), cb = bias fold
//   out = softmax(relu((1-Z)*Ht) @ Wo + bo), Z/Ht from agg@M via MFMA
//
// R1 -> R2: atomic scatter (2700us) -> CSR build + register gather.
// R3 -> R4: scatter 16x write amp -> 2-level bucket sort (793 -> 455us).
// R7 -> R8: node GEMM -> mfma_f32_16x16x32_bf16 (412 -> off top-5).
// R8 -> R9: xs = fp16(x*dinv): row 256B -> 128B (gather 124 -> 75).
// R13 -> R14: binning's global-cursor atomic serialization -> deterministic
// offsets (hist + block-scan + LDS-cursor scatter), zero global atomics
// (315 -> 304). gather now pinned at 160MB @ 3.3TB/s (L3 random service
// floor; xs 12.8MB > 4MB/XCD L2 — no cheap lever left).
// R14 -> R15: the invisible tail (~250us over 8 kernels) is led by
// node_mfma's epilogue: 102M fp32 divides (sigmoid/tanh), each a ~10-op
// correctly-rounded sequence without fast-math. Replaced with
// __builtin_amdgcn_rcpf (rel err ~1e-5 << bf16 noise).

#define SHIFT 8
#define NPB   256          // nodes per bucket (=1<<SHIFT)
#define BMAX  512          // max buckets (n <= 131072 for 17-bit src packing)
#define TILE  8192         // edges per tile (hist/scatter blocks)

typedef __attribute__((ext_vector_type(8))) short short8;
typedef __attribute__((ext_vector_type(4))) float floatx4;

__device__ __forceinline__ ushort f2b(float f) {   // fp32 -> bf16 RNE
    union { float f; unsigned u; } v; v.f = f;
    unsigned r = v.u + 0x7FFFu + ((v.u >> 16) & 1u);
    return (ushort)(r >> 16);
}

__device__ __forceinline__ float fastrcp(float x) {  // v_rcp_f32, ~1e-5 rel err
    return __builtin_amdgcn_rcpf(x);
}

// per-tile bucket histogram -> histg[block][bucket]
__global__ __launch_bounds__(512) void hist_kernel(const int* __restrict__ dsts,
                                                   int* __restrict__ histg,
                                                   int E, int B) {
    __shared__ int h[BMAX];
    for (int i = threadIdx.x; i < B; i += 512) h[i] = 0;
    __syncthreads();
    int tile0 = blockIdx.x * TILE;
#pragma unroll 4
    for (int j = 0; j < TILE / 512; ++j) {
        int e = tile0 + j * 512 + threadIdx.x;
        if (e < E) atomicAdd(&h[((unsigned)dsts[e]) >> SHIFT], 1);
    }
    __syncthreads();
    for (int i = threadIdx.x; i < B; i += 512)
        histg[blockIdx.x * BMAX + i] = h[i];
}

// one block per bucket: exclusive scan of histg[.][b] over blocks (in place),
// column total -> bdeg[b]
__global__ __launch_bounds__(512) void colscan_kernel(int* __restrict__ histg,
                                                      int* __restrict__ bdeg,
                                                      int nT) {
    int b = blockIdx.x;
    int tid = threadIdx.x;
    __shared__ int sv[512];
    int v = (tid < nT) ? histg[tid * BMAX + b] : 0;
    sv[tid] = v;
    __syncthreads();
    for (int off = 1; off < 512; off <<= 1) {
        int t = (tid >= off) ? sv[tid - off] : 0;
        __syncthreads();
        sv[tid] += t;
        __syncthreads();
    }
    if (tid < nT) histg[tid * BMAX + b] = sv[tid] - v;   // exclusive
    if (tid == 0) bdeg[b] = sv[511];                      // column total
}

__global__ __launch_bounds__(512) void bucket_prefix_kernel(const int* __restrict__ bdeg,
                                                            int* __restrict__ bbase, int B) {
    __shared__ int sv[BMAX];
    int tid = threadIdx.x;
    int v = (tid < B) ? bdeg[tid] : 0;
    sv[tid] = v;
    __syncthreads();
    for (int off = 1; off < BMAX; off <<= 1) {
        int t = (tid >= off) ? sv[tid - off] : 0;
        __syncthreads();
        sv[tid] += t;
        __syncthreads();
    }
    if (tid < B) bbase[tid] = sv[tid] - v;
}

// tile scatter with deterministic run bases (bbase[b] + histg[blk][b]) and
// LDS-only cursors — no global atomics. Packed (dstLocal<<17 | src).
__global__ __launch_bounds__(512) void scatter2_kernel(const int* __restrict__ srcs,
                                                       const int* __restrict__ dsts,
                                                       const int* __restrict__ histg,
                                                       const int* __restrict__ bbase,
                                                       int* __restrict__ staging,
                                                       int E, int B) {
    __shared__ int cur[BMAX];
    int tile0 = blockIdx.x * TILE;
    for (int i = threadIdx.x; i < B; i += 512)
        cur[i] = bbase[i] + histg[blockIdx.x * BMAX + i];
    __syncthreads();
#pragma unroll 4
    for (int j = 0; j < TILE / 512; ++j) {
        int e = tile0 + j * 512 + threadIdx.x;
        if (e < E) {
            int d = dsts[e], s = srcs[e];
            int b = ((unsigned)d) >> SHIFT;
            int pos = atomicAdd(&cur[b], 1);   // LDS atomic only
            staging[pos] = ((d & (NPB - 1)) << 17) | s;
        }
    }
}

// one block (512 thr) per bucket: per-node LDS histogram + scan ->
// start/deg/dinv, then scatter srcs inside the bucket's private csr window
__global__ __launch_bounds__(512) void finalize_kernel(const int* __restrict__ staging,
                                                       const int* __restrict__ bdeg,
                                                       const int* __restrict__ bbase,
                                                       int* __restrict__ csr,
                                                       int* __restrict__ deg,
                                                       int* __restrict__ start,
                                                       float* __restrict__ dinv, int n) {
    int b = blockIdx.x;
    int base = bbase[b], count = bdeg[b];
    __shared__ int nd[NPB];
    __shared__ int sv[NPB];
    __shared__ int ncur[NPB];
    int tid = threadIdx.x;
    if (tid < NPB) nd[tid] = 0;
    __syncthreads();
    for (int i = tid; i < count; i += 512)
        atomicAdd(&nd[staging[base + i] >> 17], 1);
    __syncthreads();
    int d0 = 0;
    if (tid < NPB) { d0 = nd[tid]; sv[tid] = d0; }
    __syncthreads();
    for (int off = 1; off < NPB; off <<= 1) {
        int t = 0;
        if (tid < NPB && tid >= off) t = sv[tid - off];
        __syncthreads();
        if (tid < NPB) sv[tid] += t;
        __syncthreads();
    }
    if (tid < NPB) {
        int excl = sv[tid] - d0;
        ncur[tid] = excl;
        int node = (b << SHIFT) + tid;
        if (node < n) {
            start[node] = base + excl;
            deg[node] = d0;
            dinv[node] = rsqrtf((float)d0 + 1.0f);
        }
    }
    __syncthreads();
    for (int i = tid; i < count; i += 512) {
        int p = staging[base + i];
        int pos = atomicAdd(&ncur[p >> 17], 1);
        csr[base + pos] = p & 0x1FFFF;
    }
}

// xs[s][c] = fp16( x[s][c] * dinv[s] ) — one thread per 4 channels
__global__ __launch_bounds__(256) void xs_kernel(const float* __restrict__ x,
                                                 const float* __restrict__ dinv,
                                                 __half* __restrict__ xs, int total) {
    int i = blockIdx.x * 256 + threadIdx.x;   // over n*16 float4 groups
    if (i >= total) return;
    float dn = dinv[i >> 4];
    float4 v = ((const float4*)x)[i];
    __half2 a = __floats2half2_rn(v.x * dn, v.y * dn);
    __half2 b = __floats2half2_rn(v.z * dn, v.w * dn);
    ((__half2*)xs)[i * 2 + 0] = a;
    ((__half2*)xs)[i * 2 + 1] = b;
}

// one wave per node. Lane = (edge_group 0..7) x (chunk 0..7). Per 64-edge
// chunk: ONE coalesced csr load (indices via shfl). Packed fp16 accumulation.
__global__ __launch_bounds__(256) void gather_kernel(const int* __restrict__ csr,
                                                     const int* __restrict__ start,
                                                     const int* __restrict__ deg,
                                                     const __half* __restrict__ xs,
                                                     const float* __restrict__ dinv,
                                                     ushort* __restrict__ aggb, int n) {
    int wave = threadIdx.x >> 6;
    int lane = threadIdx.x & 63;
    int node = blockIdx.x * 4 + wave;
    if (node >= n) return;
    int eg = lane >> 3;      // edge group 0..7
    int c  = lane & 7;       // 16B chunk (8 halfs)
    int s0 = start[node];
    int d  = deg[node];
    __half2 hz = __float2half2_rn(0.f);
    __half2 hacc[4] = {hz, hz, hz, hz};
    for (int chunk = 0; chunk < d; chunk += 64) {
        int nrem = d - chunk;
        if (nrem > 64) nrem = 64;
        int ml = lane < nrem ? lane : nrem - 1;
        int idx = csr[s0 + chunk + ml];          // one coalesced load / chunk
        int full = nrem & ~15;
        for (int base = 0; base < full; base += 16) {   // unpredicated batches
            int i0 = __shfl(idx, base + eg);
            int i1 = __shfl(idx, base + 8 + eg);
            union { uint4 u; __half2 h[4]; } p0, p1;
            p0.u = *(const uint4*)(xs + (size_t)i0 * 64 + c * 8);
            p1.u = *(const uint4*)(xs + (size_t)i1 * 64 + c * 8);
#pragma unroll
            for (int t = 0; t < 4; ++t) hacc[t] = __hadd2(hacc[t], p0.h[t]);
#pragma unroll
            for (int t = 0; t < 4; ++t) hacc[t] = __hadd2(hacc[t], p1.h[t]);
        }
        if (full < nrem) {   // wave-uniform ragged tail (< 16 edges)
            int e0 = full + eg;
            int e1 = full + 8 + eg;
            int i0 = __shfl(idx, e0 < nrem ? e0 : nrem - 1);
            int i1 = __shfl(idx, e1 < nrem ? e1 : nrem - 1);
            union { uint4 u; __half2 h[4]; } p0, p1;
            p0.u = *(const uint4*)(xs + (size_t)i0 * 64 + c * 8);
            p1.u = *(const uint4*)(xs + (size_t)i1 * 64 + c * 8);
            if (e0 >= nrem) p0.u = make_uint4(0u, 0u, 0u, 0u);
            if (e1 >= nrem) p1.u = make_uint4(0u, 0u, 0u, 0u);
#pragma unroll
            for (int t = 0; t < 4; ++t) hacc[t] = __hadd2(hacc[t], p0.h[t]);
#pragma unroll
            for (int t = 0; t < 4; ++t) hacc[t] = __hadd2(hacc[t], p1.h[t]);
        }
    }
    // packed cross-lane reduce of the 8 edge groups down to eg==0
#pragma unroll
    for (int off = 32; off >= 8; off >>= 1) {
#pragma unroll
        for (int t = 0; t < 4; ++t) {
            union { __half2 h; int i; } u;
            u.h = hacc[t];
            u.i = __shfl_down(u.i, off);
            hacc[t] = __hadd2(hacc[t], u.h);
        }
    }
    if (eg == 0) {
        float dn = dinv[node];
        union { uint4 u; __half2 h[4]; } p;
        p.u = *(const uint4*)(xs + (size_t)node * 64 + c * 8);
        uint4 o;
        unsigned* ow = (unsigned*)&o;
#pragma unroll
        for (int t = 0; t < 4; ++t) {
            float2 a = __half22float2(hacc[t]);
            float2 f = __half22float2(p.h[t]);
            float v0 = dn * fmaf(f.x, dn, a.x);
            float v1 = dn * fmaf(f.y, dn, a.y);
            ow[t] = (unsigned)f2b(v0) | ((unsigned)f2b(v1) << 16);
        }
        ((uint4*)(aggb + (size_t)node * 64))[c] = o;
    }
}

// Mb[j][k] = bf16( sum_t W[k][t] * L[t][j] ), j in [0,512): j<256 z, else h.
// Row-major [512][64] bf16 == MFMA B-operand order. cb[j] = bias fold.
__global__ __launch_bounds__(64) void build_m_kernel(
    const float* __restrict__ Wz, const float* __restrict__ bz,
    const float* __restrict__ Wh, const float* __restrict__ bh,
    const float* __restrict__ Lzw, const float* __restrict__ Lzb,
    const float* __restrict__ Lhw, const float* __restrict__ Lhb,
    ushort* __restrict__ Mb, float* __restrict__ cb) {
    int j = blockIdx.x;          // 0..511
    int k = threadIdx.x;         // 0..63
    int which = j >> 8;
    int jj = j & 255;
    const float* W  = which ? Wh  : Wz;
    const float* bv = which ? bh  : bz;
    const float* L  = which ? Lhw : Lzw;   // [512,256]; rows 0..255 only (H0=0)
    const float* Lb = which ? Lhb : Lzb;
    float acc = 0.f;
    for (int t = 0; t < 256; ++t) acc = fmaf(W[k * 256 + t], L[t * 256 + jj], acc);
    Mb[j * 64 + k] = f2b(acc);
    if (k == 0) {
        float a = 0.f;
        for (int t = 0; t < 256; ++t) a = fmaf(bv[t], L[t * 256 + jj], a);
        cb[j] = a + Lb[jj];
    }
}

// 512 threads = 8 waves. Wave w owns cols w*32..w*32+31 for BOTH gates
// (z and ht meet in-register, h=relu((1-z)*ht) -> one h-plane in LDS).
// 32-node tiles: 16 MFMA between barriers, head 16 thr/node, grid 1024
// co-resident. R15: all 1/x via v_rcp_f32 — the IEEE div sequence was
// ~10 VALU ops x 102M divides in this epilogue.
__global__ __launch_bounds__(512) void node_mfma_kernel(
    const ushort* __restrict__ aggb,   // [n][64] bf16
    const ushort* __restrict__ Mb,     // [512][64] bf16 (B layout)
    const float* __restrict__ cb,      // [512]
    const float* __restrict__ Wo, const float* __restrict__ bo,
    float* __restrict__ out, int n) {
    int tid  = threadIdx.x;
    int w    = tid >> 6;
    int lane = tid & 63;
    int nidx = lane & 15;
    int quad = lane >> 4;
    short8 bfz[2][2], bfh[2][2];
    float cbz[2], cbh[2];
#pragma unroll
    for (int cg = 0; cg < 2; ++cg) {
        int colZ = (w << 5) + (cg << 4) + nidx;
        int colH = 256 + colZ;
#pragma unroll
        for (int s = 0; s < 2; ++s) {
            bfz[cg][s] = *(const short8*)(Mb + colZ * 64 + s * 32 + quad * 8);
            bfh[cg][s] = *(const short8*)(Mb + colH * 64 + s * 32 + quad * 8);
        }
        cbz[cg] = cb[colZ];
        cbh[cg] = cb[colH];
    }
    __shared__ float sH[32][260];    // 33 KB h-plane (260 pad: 2-way on stores)
    __shared__ float sWo[4][256];
    if (tid < 256) {
#pragma unroll
        for (int o = 0; o < 4; ++o) sWo[o][tid] = Wo[tid * 4 + o];
    }
    float bo0 = bo[0], bo1 = bo[1], bo2 = bo[2], bo3 = bo[3];
    int ntiles = (n + 31) >> 5;
    for (int tile = blockIdx.x; tile < ntiles; tile += gridDim.x) {
        int node0 = tile << 5;
        int nA0 = node0 + nidx;
        int nA1 = node0 + 16 + nidx;
        if (nA0 >= n) nA0 = n - 1;   // clamp; stores are guarded
        if (nA1 >= n) nA1 = n - 1;
        const ushort* ar0 = aggb + (size_t)nA0 * 64;
        const ushort* ar1 = aggb + (size_t)nA1 * 64;
        short8 a00 = *(const short8*)(ar0 + quad * 8);
        short8 a01 = *(const short8*)(ar0 + 32 + quad * 8);
        short8 a10 = *(const short8*)(ar1 + quad * 8);
        short8 a11 = *(const short8*)(ar1 + 32 + quad * 8);
#pragma unroll
        for (int cg = 0; cg < 2; ++cg) {
            int col = (w << 5) + (cg << 4) + nidx;
#pragma unroll
            for (int grp = 0; grp < 2; ++grp) {
                short8 a0 = grp ? a10 : a00;
                short8 a1 = grp ? a11 : a01;
                floatx4 cz = {cbz[cg], cbz[cg], cbz[cg], cbz[cg]};
                cz = __builtin_amdgcn_mfma_f32_16x16x32_bf16(a0, bfz[cg][0], cz, 0, 0, 0);
                cz = __builtin_amdgcn_mfma_f32_16x16x32_bf16(a1, bfz[cg][1], cz, 0, 0, 0);
                floatx4 chh = {cbh[cg], cbh[cg], cbh[cg], cbh[cg]};
                chh = __builtin_amdgcn_mfma_f32_16x16x32_bf16(a0, bfh[cg][0], chh, 0, 0, 0);
                chh = __builtin_amdgcn_mfma_f32_16x16x32_bf16(a1, bfh[cg][1], chh, 0, 0, 0);
#pragma unroll
                for (int r = 0; r < 4; ++r) {
                    int row = (grp << 4) + (quad << 2) + r;   // node within tile
                    float zc = fastrcp(1.0f + __expf(cz[r]));     // 1 - sigmoid
                    float th = 1.0f - 2.0f * fastrcp(1.0f + __expf(2.0f * chh[r]));
                    sH[row][col] = fmaxf(zc * th, 0.0f);
                }
            }
        }
        __syncthreads();
        {   // head: 16 threads per node, 16 channels each
            int nb = tid >> 4, g = tid & 15;
            float l0 = 0.f, l1 = 0.f, l2 = 0.f, l3 = 0.f;
#pragma unroll
            for (int ii = 0; ii < 16; ++ii) {
                int ch = g + 16 * ii;
                float hv = sH[nb][ch];
                l0 = fmaf(hv, sWo[0][ch], l0);
                l1 = fmaf(hv, sWo[1][ch], l1);
                l2 = fmaf(hv, sWo[2][ch], l2);
                l3 = fmaf(hv, sWo[3][ch], l3);
            }
#pragma unroll
            for (int off = 8; off > 0; off >>= 1) {
                l0 += __shfl_down(l0, off, 16);
                l1 += __shfl_down(l1, off, 16);
                l2 += __shfl_down(l2, off, 16);
                l3 += __shfl_down(l3, off, 16);
            }
            int node = node0 + nb;
            if (g == 0 && node < n) {
                float v0 = l0 + bo0, v1 = l1 + bo1, v2 = l2 + bo2, v3 = l3 + bo3;
                float mx = fmaxf(fmaxf(v0, v1), fmaxf(v2, v3));
                float e0 = __expf(v0 - mx), e1 = __expf(v1 - mx);
                float e2 = __expf(v2 - mx), e3 = __expf(v3 - mx);
                float inv = fastrcp(e0 + e1 + e2 + e3);
                float4 o;
                o.x = e0 * inv; o.y = e1 * inv; o.z = e2 * inv; o.w = e3 * inv;
                ((float4*)out)[node] = o;
            }
        }
        __syncthreads();
    }
}

extern "C" void kernel_launch(void* const* d_in, const int* in_sizes, int n_in,
                              void* d_out, int out_size, void* d_ws, size_t ws_size,
                              hipStream_t stream) {
    const float* x   = (const float*)d_in[0];
    const int*  eidx = (const int*)d_in[1];
    const float* Wz  = (const float*)d_in[2];
    const float* bz  = (const float*)d_in[3];
    // d_in[4]=Wr, d_in[5]=br : dead (H0 = 0)
    const float* Wh  = (const float*)d_in[6];
    const float* bh  = (const float*)d_in[7];
    const float* Lzw = (const float*)d_in[8];
    const float* Lzb = (const float*)d_in[9];
    // d_in[10]=Lrw, d_in[11]=Lrb : dead
    const float* Lhw = (const float*)d_in[12];
    const float* Lhb = (const float*)d_in[13];
    const float* Wo  = (const float*)d_in[14];
    const float* bo  = (const float*)d_in[15];
    float* out = (float*)d_out;

    int n = in_sizes[0] / 64;
    int E = in_sizes[1] / 2;
    const int* srcs = eidx;
    const int* dsts = eidx + E;
    int B = (n + NPB - 1) >> SHIFT;
    int nT = (E + TILE - 1) / TILE;          // tiles (<= 512 for E <= 4.2M)

    size_t na = ((size_t)n + 3) & ~(size_t)3;
    size_t aggBytes = (size_t)n * 64 * 2;                 // bf16 agg
    size_t stageBytes = (size_t)E * 4 + 16;               // staging (aliases agg)
    size_t bigBytes = (aggBytes > stageBytes ? aggBytes : stageBytes);
    bigBytes = (bigBytes + 255) & ~(size_t)255;

    char* ws = (char*)d_ws;
    int*   deg   = (int*)ws;    ws += na * 4;
    int*   start = (int*)ws;    ws += na * 4;
    float* dinv  = (float*)ws;  ws += na * 4;
    int*   bdeg  = (int*)ws;    ws += BMAX * 4;
    int*   bbase = (int*)ws;    ws += BMAX * 4;
    int*   histg = (int*)ws;    ws += (size_t)nT * BMAX * 4;
    int*   csr   = (int*)ws;    ws += (size_t)E * 4;
    __half* xs   = (__half*)ws; ws += (size_t)n * 64 * 2;
    ushort* aggb = (ushort*)ws;
    int*   staging = (int*)aggb;   // aliases aggb: staging dead before gather
    ws += bigBytes;
    ushort* Mb   = (ushort*)ws; ws += 512 * 64 * 2;
    float* cb    = (float*)ws;  ws += 512 * 4;

    hist_kernel<<<nT, 512, 0, stream>>>(dsts, histg, E, B);
    colscan_kernel<<<B, 512, 0, stream>>>(histg, bdeg, nT);
    bucket_prefix_kernel<<<1, BMAX, 0, stream>>>(bdeg, bbase, B);
    scatter2_kernel<<<nT, 512, 0, stream>>>(srcs, dsts, histg, bbase, staging,
                                            E, B);
    finalize_kernel<<<B, 512, 0, stream>>>(staging, bdeg, bbase, csr, deg, start,
                                           dinv, n);
    build_m_kernel<<<512, 64, 0, stream>>>(Wz, bz, Wh, bh, Lzw, Lzb, Lhw, Lhb,
                                           Mb, cb);
    xs_kernel<<<(n * 16 + 255) / 256, 256, 0, stream>>>(x, dinv, xs, n * 16);
    gather_kernel<<<(n + 3) / 4, 256, 0, stream>>>(csr, start, deg, xs, dinv,
                                                   aggb, n);
    node_mfma_kernel<<<1024, 512, 0, stream>>>(aggb, Mb, cb, Wo, bo, out, n);
}